// Round 1
// baseline (556.018 us; speedup 1.0000x reference)
//
#include <hip/hip_runtime.h>
#include <math.h>

#define EPSF 0.3f

// ---------------- edge dtype probe (int32 vs int64) ----------------
// If edge_index is int64 on device, every odd 32-bit word is a zero high
// word (values < 50000). If int32, odd words are random indices.
__global__ void k_detect(const int* __restrict__ ei, int* __restrict__ flag) {
    __shared__ int nz;
    if (threadIdx.x == 0) nz = 0;
    __syncthreads();
    for (int t = threadIdx.x; t < 2048; t += 256)
        if (ei[2 * t + 1] != 0) atomicOr(&nz, 1);
    __syncthreads();
    if (threadIdx.x == 0) flag[0] = (nz == 0) ? 1 : 0;  // 1 => int64
}

__device__ __forceinline__ int edge_at(const int* ei, int is64, size_t idx) {
    if (is64) return (int)((const long long*)ei)[idx];
    return ei[idx];
}

// ---------------- degree / CSR build ----------------
__global__ void k_deg(const int* __restrict__ ei, int E, int* __restrict__ deg,
                      const int* __restrict__ flag) {
    int e = blockIdx.x * blockDim.x + threadIdx.x;
    if (e < E) {
        int r = edge_at(ei, flag[0], e);
        atomicAdd(&deg[r], 1);
    }
}

__global__ void k_dinv(const int* __restrict__ deg, float* __restrict__ dinv, int N) {
    int i = blockIdx.x * blockDim.x + threadIdx.x;
    if (i < N) {
        int d = deg[i];
        dinv[i] = d > 0 ? rsqrtf((float)d) : 0.f;
    }
}

__global__ void k_scan1(const int* __restrict__ deg, int* __restrict__ rp,
                        int* __restrict__ bsum, int N) {
    __shared__ int s[1024];
    int t = threadIdx.x;
    int i = blockIdx.x * 1024 + t;
    int v = (i < N) ? deg[i] : 0;
    s[t] = v;
    __syncthreads();
    for (int o = 1; o < 1024; o <<= 1) {
        int x = (t >= o) ? s[t - o] : 0;
        __syncthreads();
        s[t] += x;
        __syncthreads();
    }
    if (i < N) rp[i] = s[t] - v;  // exclusive within block
    if (t == 1023) bsum[blockIdx.x] = s[t];
}

__global__ void k_scan2(int* __restrict__ bsum, int nb, int* __restrict__ rp, int N) {
    if (threadIdx.x == 0 && blockIdx.x == 0) {
        int run = 0;
        for (int b = 0; b < nb; ++b) { int v = bsum[b]; bsum[b] = run; run += v; }
        rp[N] = run;
    }
}

__global__ void k_scan3(int* __restrict__ rp, const int* __restrict__ bsum,
                        int* __restrict__ cur, int N) {
    int i = blockIdx.x * blockDim.x + threadIdx.x;
    if (i < N) {
        int v = rp[i] + bsum[i >> 10];
        rp[i] = v;
        cur[i] = v;
    }
}

__global__ void k_scatter(const int* __restrict__ ei, int E,
                          const float* __restrict__ dinv, int* __restrict__ cur,
                          int* __restrict__ ecol, float* __restrict__ ew,
                          const int* __restrict__ flag) {
    int e = blockIdx.x * blockDim.x + threadIdx.x;
    if (e < E) {
        int is64 = flag[0];
        int r = edge_at(ei, is64, e);
        int c = edge_at(ei, is64, (size_t)E + e);
        int pos = atomicAdd(&cur[r], 1);
        ecol[pos] = c;
        ew[pos] = dinv[r] * dinv[c];
    }
}

// ---------------- tiled fp32 GEMM: C = A(MxK) * W(NxK)^T + bias ----------------
template <int BM, int BN, int BK, bool RELU>
__global__ __launch_bounds__(256) void k_gemm(const float* __restrict__ A,
                                              const float* __restrict__ W,
                                              const float* __restrict__ bias,
                                              float* __restrict__ C,
                                              int M, int N, int K) {
    constexpr int TM = BM / 16, TN = BN / 16;
    __shared__ float As[BK][BM + 4];
    __shared__ float Bs[BK][BN + 4];
    const int tid = threadIdx.x;
    const int tm = (tid / 16) * TM, tn = (tid % 16) * TN;
    const int m0 = blockIdx.x * BM, n0 = blockIdx.y * BN;
    float acc[TM][TN] = {};
    for (int k0 = 0; k0 < K; k0 += BK) {
#pragma unroll
        for (int r0 = 0; r0 < BM; r0 += 64) {
            int m = r0 + (tid >> 2);
            int kq = (tid & 3) * 4;
            float4 v = make_float4(0.f, 0.f, 0.f, 0.f);
            if (m0 + m < M) v = *(const float4*)&A[(size_t)(m0 + m) * K + k0 + kq];
            As[kq + 0][m] = v.x; As[kq + 1][m] = v.y;
            As[kq + 2][m] = v.z; As[kq + 3][m] = v.w;
        }
#pragma unroll
        for (int r0 = 0; r0 < BN; r0 += 64) {
            int n = r0 + (tid >> 2);
            int kq = (tid & 3) * 4;
            float4 v = *(const float4*)&W[(size_t)(n0 + n) * K + k0 + kq];
            Bs[kq + 0][n] = v.x; Bs[kq + 1][n] = v.y;
            Bs[kq + 2][n] = v.z; Bs[kq + 3][n] = v.w;
        }
        __syncthreads();
#pragma unroll
        for (int kk = 0; kk < BK; ++kk) {
            float a[TM], b[TN];
#pragma unroll
            for (int x = 0; x < TM; x += 4)
                *(float4*)&a[x] = *(const float4*)&As[kk][tm + x];
#pragma unroll
            for (int x = 0; x < TN; x += 4)
                *(float4*)&b[x] = *(const float4*)&Bs[kk][tn + x];
#pragma unroll
            for (int mi = 0; mi < TM; ++mi)
#pragma unroll
                for (int ni = 0; ni < TN; ++ni)
                    acc[mi][ni] = fmaf(a[mi], b[ni], acc[mi][ni]);
        }
        __syncthreads();
    }
#pragma unroll
    for (int mi = 0; mi < TM; ++mi) {
        int m = m0 + tm + mi;
        if (m < M) {
#pragma unroll
            for (int ni = 0; ni < TN; ++ni) {
                float v = acc[mi][ni] + bias[n0 + tn + ni];
                if (RELU) v = fmaxf(v, 0.f);
                C[(size_t)m * N + n0 + tn + ni] = v;
            }
        }
    }
}

// ---------------- per-node gate scalars: a[i]=h[i].gw_i, b[i]=h[i].gw_j ----------------
__global__ void k_ab(const float* __restrict__ h, const float* __restrict__ gw,
                     float* __restrict__ a, float* __restrict__ b, int N) {
    int wid = threadIdx.x >> 6, lane = threadIdx.x & 63;
    int i = blockIdx.x * 4 + wid;
    if (i >= N) return;
    float2 hv = *(const float2*)&h[(size_t)i * 128 + lane * 2];
    float2 wi = *(const float2*)&gw[lane * 2];
    float2 wj = *(const float2*)&gw[128 + lane * 2];
    float pa = hv.x * wi.x + hv.y * wi.y;
    float pb = hv.x * wj.x + hv.y * wj.y;
    for (int o = 1; o < 64; o <<= 1) {
        pa += __shfl_xor(pa, o);
        pb += __shfl_xor(pb, o);
    }
    if (lane == 0) { a[i] = pa; b[i] = pb; }
}

// ---------------- aggregation: h_out[i] = EPS*raw[i] + sum_e w_e * h_in[col_e] ----------------
__global__ void k_agg(const float* __restrict__ h_in, const float* __restrict__ raw,
                      const int* __restrict__ rp, const int* __restrict__ ecol,
                      const float* __restrict__ ew, const float* __restrict__ a,
                      const float* __restrict__ b, const float* __restrict__ gb,
                      int layer, float* __restrict__ h_out, int N) {
    int wid = threadIdx.x >> 6, lane = threadIdx.x & 63;
    int i = blockIdx.x * 4 + wid;
    if (i >= N) return;
    float a_i = a[i] + gb[layer];
    int p0 = rp[i], p1 = rp[i + 1];
    float acc0 = 0.f, acc1 = 0.f;
    for (int base = p0; base < p1; base += 64) {
        int p = base + lane;
        float w = 0.f;
        int c = 0;
        if (p < p1) {
            c = ecol[p];
            w = tanhf(a_i + b[c]) * ew[p];
        }
        int cnt = min(64, p1 - base);
        for (int k = 0; k < cnt; ++k) {
            float wk = __shfl(w, k);
            int ck = __shfl(c, k);
            float2 hv = *(const float2*)&h_in[(size_t)ck * 128 + lane * 2];
            acc0 = fmaf(wk, hv.x, acc0);
            acc1 = fmaf(wk, hv.y, acc1);
        }
    }
    float2 rv = *(const float2*)&raw[(size_t)i * 128 + lane * 2];
    float2 o;
    o.x = EPSF * rv.x + acc0;
    o.y = EPSF * rv.y + acc1;
    *(float2*)&h_out[(size_t)i * 128 + lane * 2] = o;
}

// ---------------- log_softmax over 64 outputs, one wave per node ----------------
__global__ void k_logsm(float* __restrict__ out, int N) {
    int wid = threadIdx.x >> 6, lane = threadIdx.x & 63;
    int i = blockIdx.x * 4 + wid;
    if (i >= N) return;
    float v = out[(size_t)i * 64 + lane];
    float m = v;
    for (int o = 1; o < 64; o <<= 1) m = fmaxf(m, __shfl_xor(m, o));
    float e = expf(v - m);
    float s = e;
    for (int o = 1; o < 64; o <<= 1) s += __shfl_xor(s, o);
    out[(size_t)i * 64 + lane] = v - m - logf(s);
}

extern "C" void kernel_launch(void* const* d_in, const int* in_sizes, int n_in,
                              void* d_out, int out_size, void* d_ws, size_t ws_size,
                              hipStream_t stream) {
    const float* x = (const float*)d_in[0];
    const int* ei = (const int*)d_in[1];
    const float* t1w = (const float*)d_in[2];
    const float* t1b = (const float*)d_in[3];
    const float* gw = (const float*)d_in[4];
    const float* gb = (const float*)d_in[5];
    const float* t2w = (const float*)d_in[6];
    const float* t2b = (const float*)d_in[7];
    float* out = (float*)d_out;

    const int INC = 256, HID = 128, OUTC = 64;
    const int N = in_sizes[0] / INC;
    const int E = in_sizes[1] / 2;
    const int nb = (N + 1023) / 1024;

    char* ws = (char*)d_ws;
    auto alloc = [&](size_t bytes) {
        char* p = ws;
        ws += (bytes + 255) & ~(size_t)255;
        return p;
    };
    int* flag = (int*)alloc(4);
    int* deg = (int*)alloc((size_t)N * 4);
    float* dinv = (float*)alloc((size_t)N * 4);
    int* rp = (int*)alloc((size_t)(N + 1) * 4);
    int* cur = (int*)alloc((size_t)N * 4);
    int* bsum = (int*)alloc((size_t)nb * 4);
    int* ecol = (int*)alloc((size_t)E * 4);
    float* ewt = (float*)alloc((size_t)E * 4);
    float* av = (float*)alloc((size_t)N * 4);
    float* bv = (float*)alloc((size_t)N * 4);
    float* h0 = (float*)alloc((size_t)N * HID * 4);
    float* h1 = (float*)alloc((size_t)N * HID * 4);

    hipMemsetAsync(deg, 0, (size_t)N * 4, stream);
    k_detect<<<1, 256, 0, stream>>>(ei, flag);
    k_deg<<<(E + 255) / 256, 256, 0, stream>>>(ei, E, deg, flag);
    k_dinv<<<(N + 255) / 256, 256, 0, stream>>>(deg, dinv, N);
    k_scan1<<<nb, 1024, 0, stream>>>(deg, rp, bsum, N);
    k_scan2<<<1, 64, 0, stream>>>(bsum, nb, rp, N);
    k_scan3<<<(N + 255) / 256, 256, 0, stream>>>(rp, bsum, cur, N);
    k_scatter<<<(E + 255) / 256, 256, 0, stream>>>(ei, E, dinv, cur, ecol, ewt, flag);

    // h0 = relu(x @ t1_w^T + t1_b)   (raw)
    k_gemm<128, 128, 16, true>
        <<<dim3((N + 127) / 128, 1), 256, 0, stream>>>(x, t1w, t1b, h0, N, HID, INC);

    // layer 0: h0 -> h1
    k_ab<<<(N + 3) / 4, 256, 0, stream>>>(h0, gw + 0 * 256, av, bv, N);
    k_agg<<<(N + 3) / 4, 256, 0, stream>>>(h0, h0, rp, ecol, ewt, av, bv, gb, 0, h1, N);
    // layer 1: h1 -> h0 (raw = h0; epilogue-only read of own node => safe in-place)
    k_ab<<<(N + 3) / 4, 256, 0, stream>>>(h1, gw + 1 * 256, av, bv, N);
    k_agg<<<(N + 3) / 4, 256, 0, stream>>>(h1, h0, rp, ecol, ewt, av, bv, gb, 1, h0, N);

    // out = h0 @ t2_w^T + t2_b, then log_softmax in place
    k_gemm<128, 64, 16, false>
        <<<dim3((N + 127) / 128, 1), 256, 0, stream>>>(h0, t2w, t2b, out, N, OUTC, HID);
    k_logsm<<<(N + 3) / 4, 256, 0, stream>>>(out, N);
}

// Round 2
// 442.564 us; speedup vs baseline: 1.2564x; 1.2564x over previous
//
#include <hip/hip_runtime.h>
#include <math.h>

#define EPSF 0.3f

// ---------------- bf16 helpers ----------------
__device__ __forceinline__ uint32_t f2bf(float f) {
    uint32_t u = __float_as_uint(f);
    return (u + 0x7fffu + ((u >> 16) & 1u)) >> 16;  // RNE
}
__device__ __forceinline__ uint32_t pack2(float lo, float hi) {
    return f2bf(lo) | (f2bf(hi) << 16);
}
__device__ __forceinline__ float bflo(uint32_t u) { return __uint_as_float(u << 16); }
__device__ __forceinline__ float bfhi(uint32_t u) { return __uint_as_float(u & 0xffff0000u); }

// ---------------- edge dtype probe (int32 vs int64) ----------------
__global__ void k_detect(const int* __restrict__ ei, int* __restrict__ flag) {
    __shared__ int nz;
    if (threadIdx.x == 0) nz = 0;
    __syncthreads();
    for (int t = threadIdx.x; t < 2048; t += 256)
        if (ei[2 * t + 1] != 0) atomicOr(&nz, 1);
    __syncthreads();
    if (threadIdx.x == 0) flag[0] = (nz == 0) ? 1 : 0;  // 1 => int64
}

__device__ __forceinline__ int edge_at(const int* ei, int is64, size_t idx) {
    if (is64) return (int)((const long long*)ei)[idx];
    return ei[idx];
}

// ---------------- degree / CSR build ----------------
__global__ void k_deg(const int* __restrict__ ei, int E, int* __restrict__ deg,
                      const int* __restrict__ flag) {
    int e = blockIdx.x * blockDim.x + threadIdx.x;
    if (e < E) {
        int r = edge_at(ei, flag[0], e);
        atomicAdd(&deg[r], 1);
    }
}

__global__ void k_dinv(const int* __restrict__ deg, float* __restrict__ dinv, int N) {
    int i = blockIdx.x * blockDim.x + threadIdx.x;
    if (i < N) {
        int d = deg[i];
        dinv[i] = d > 0 ? rsqrtf((float)d) : 0.f;
    }
}

__global__ void k_scan1(const int* __restrict__ deg, int* __restrict__ rp,
                        int* __restrict__ bsum, int N) {
    __shared__ int s[1024];
    int t = threadIdx.x;
    int i = blockIdx.x * 1024 + t;
    int v = (i < N) ? deg[i] : 0;
    s[t] = v;
    __syncthreads();
    for (int o = 1; o < 1024; o <<= 1) {
        int x = (t >= o) ? s[t - o] : 0;
        __syncthreads();
        s[t] += x;
        __syncthreads();
    }
    if (i < N) rp[i] = s[t] - v;
    if (t == 1023) bsum[blockIdx.x] = s[t];
}

__global__ void k_scan2(int* __restrict__ bsum, int nb, int* __restrict__ rp, int N) {
    if (threadIdx.x == 0 && blockIdx.x == 0) {
        int run = 0;
        for (int b = 0; b < nb; ++b) { int v = bsum[b]; bsum[b] = run; run += v; }
        rp[N] = run;
    }
}

__global__ void k_scan3(int* __restrict__ rp, const int* __restrict__ bsum,
                        int* __restrict__ cur, int N) {
    int i = blockIdx.x * blockDim.x + threadIdx.x;
    if (i < N) {
        int v = rp[i] + bsum[i >> 10];
        rp[i] = v;
        cur[i] = v;
    }
}

// scatter: one 4B random write per edge (ew is recomputed later from bd table)
__global__ void k_scatter(const int* __restrict__ ei, int E, int* __restrict__ cur,
                          int* __restrict__ ecol, const int* __restrict__ flag) {
    int e = blockIdx.x * blockDim.x + threadIdx.x;
    if (e < E) {
        int is64 = flag[0];
        int r = edge_at(ei, is64, e);
        int c = edge_at(ei, is64, (size_t)E + e);
        int pos = atomicAdd(&cur[r], 1);
        ecol[pos] = c;
    }
}

// ---------------- tiled fp32 GEMM: C = A(MxK) * W(NxK)^T + bias ----------------
template <int BM, int BN, int BK, bool RELU, bool WBF16>
__global__ __launch_bounds__(256) void k_gemm(const float* __restrict__ A,
                                              const float* __restrict__ W,
                                              const float* __restrict__ bias,
                                              float* __restrict__ C,
                                              uint32_t* __restrict__ hb,
                                              int M, int N, int K) {
    constexpr int TM = BM / 16, TN = BN / 16;
    __shared__ float As[BK][BM + 4];
    __shared__ float Bs[BK][BN + 4];
    const int tid = threadIdx.x;
    const int tm = (tid / 16) * TM, tn = (tid % 16) * TN;
    const int m0 = blockIdx.x * BM, n0 = blockIdx.y * BN;
    float acc[TM][TN] = {};
    for (int k0 = 0; k0 < K; k0 += BK) {
#pragma unroll
        for (int r0 = 0; r0 < BM; r0 += 64) {
            int m = r0 + (tid >> 2);
            int kq = (tid & 3) * 4;
            float4 v = make_float4(0.f, 0.f, 0.f, 0.f);
            if (m0 + m < M) v = *(const float4*)&A[(size_t)(m0 + m) * K + k0 + kq];
            As[kq + 0][m] = v.x; As[kq + 1][m] = v.y;
            As[kq + 2][m] = v.z; As[kq + 3][m] = v.w;
        }
#pragma unroll
        for (int r0 = 0; r0 < BN; r0 += 64) {
            int n = r0 + (tid >> 2);
            int kq = (tid & 3) * 4;
            float4 v = *(const float4*)&W[(size_t)(n0 + n) * K + k0 + kq];
            Bs[kq + 0][n] = v.x; Bs[kq + 1][n] = v.y;
            Bs[kq + 2][n] = v.z; Bs[kq + 3][n] = v.w;
        }
        __syncthreads();
#pragma unroll
        for (int kk = 0; kk < BK; ++kk) {
            float a[TM], b[TN];
#pragma unroll
            for (int x = 0; x < TM; x += 4)
                *(float4*)&a[x] = *(const float4*)&As[kk][tm + x];
#pragma unroll
            for (int x = 0; x < TN; x += 4)
                *(float4*)&b[x] = *(const float4*)&Bs[kk][tn + x];
#pragma unroll
            for (int mi = 0; mi < TM; ++mi)
#pragma unroll
                for (int ni = 0; ni < TN; ++ni)
                    acc[mi][ni] = fmaf(a[mi], b[ni], acc[mi][ni]);
        }
        __syncthreads();
    }
#pragma unroll
    for (int mi = 0; mi < TM; ++mi) {
        int m = m0 + tm + mi;
        if (m < M) {
            float vv[TN];
#pragma unroll
            for (int ni = 0; ni < TN; ++ni) {
                float v = acc[mi][ni] + bias[n0 + tn + ni];
                if (RELU) v = fmaxf(v, 0.f);
                C[(size_t)m * N + n0 + tn + ni] = v;
                vv[ni] = v;
            }
            if (WBF16) {
                // TN==8 path only: pack 8 floats -> 4 uints -> one uint4 store
                uint4 pk;
                pk.x = pack2(vv[0], vv[1]);
                pk.y = pack2(vv[2], vv[3]);
                pk.z = pack2(vv[4], vv[5]);
                pk.w = pack2(vv[6], vv[7]);
                *(uint4*)&hb[(size_t)m * 64 + (size_t)(n0 + tn) / 2] = pk;
            }
        }
    }
}

// ---------------- per-node gate scalars ----------------
// av[i] = h[i].gw_i + gate_b[layer];  bd[i] = {h[i].gw_j, dinv[i]}
__global__ void k_ab(const float* __restrict__ h, const float* __restrict__ gw,
                     const float* __restrict__ gb, int layer,
                     const float* __restrict__ dinv,
                     float* __restrict__ av, float2* __restrict__ bd, int N) {
    int wid = threadIdx.x >> 6, lane = threadIdx.x & 63;
    int i = blockIdx.x * 4 + wid;
    if (i >= N) return;
    float2 hv = *(const float2*)&h[(size_t)i * 128 + lane * 2];
    float2 wi = *(const float2*)&gw[lane * 2];
    float2 wj = *(const float2*)&gw[128 + lane * 2];
    float pa = hv.x * wi.x + hv.y * wi.y;
    float pb = hv.x * wj.x + hv.y * wj.y;
    for (int o = 1; o < 64; o <<= 1) {
        pa += __shfl_xor(pa, o);
        pb += __shfl_xor(pb, o);
    }
    if (lane == 0) {
        av[i] = pa + gb[layer];
        bd[i] = make_float2(pb, dinv[i]);
    }
}

// ---------------- aggregation ----------------
// h_out[i] = EPS*raw[i] + dinv[i] * sum_e tanh(av[i]+b[c])*dinv[c] * h_bf16[c]
__global__ void k_agg(const uint32_t* __restrict__ hb, const float* __restrict__ raw,
                      const int* __restrict__ rp, const int* __restrict__ ecol,
                      const float* __restrict__ av, const float2* __restrict__ bd,
                      float* __restrict__ h_out, uint32_t* __restrict__ hb_out, int N) {
    int wid = threadIdx.x >> 6, lane = threadIdx.x & 63;
    int i = blockIdx.x * 4 + wid;
    if (i >= N) return;
    float a_i = av[i];
    float dinv_i = bd[i].y;
    int p0 = rp[i], p1 = rp[i + 1];
    float acc0 = 0.f, acc1 = 0.f;
    for (int base = p0; base < p1; base += 64) {
        int p = base + lane;
        float w = 0.f;
        int c = 0;
        if (p < p1) {
            c = ecol[p];
            float2 t = bd[c];
            w = tanhf(a_i + t.x) * t.y;  // dinv_i folded at the end
        }
        int cnt = min(64, p1 - base);
        int k = 0;
        for (; k + 4 <= cnt; k += 4) {
            float w0 = __shfl(w, k + 0), w1 = __shfl(w, k + 1);
            float w2 = __shfl(w, k + 2), w3 = __shfl(w, k + 3);
            int c0 = __shfl(c, k + 0), c1 = __shfl(c, k + 1);
            int c2 = __shfl(c, k + 2), c3 = __shfl(c, k + 3);
            uint32_t u0 = hb[(size_t)c0 * 64 + lane];
            uint32_t u1 = hb[(size_t)c1 * 64 + lane];
            uint32_t u2 = hb[(size_t)c2 * 64 + lane];
            uint32_t u3 = hb[(size_t)c3 * 64 + lane];
            acc0 = fmaf(w0, bflo(u0), acc0); acc1 = fmaf(w0, bfhi(u0), acc1);
            acc0 = fmaf(w1, bflo(u1), acc0); acc1 = fmaf(w1, bfhi(u1), acc1);
            acc0 = fmaf(w2, bflo(u2), acc0); acc1 = fmaf(w2, bfhi(u2), acc1);
            acc0 = fmaf(w3, bflo(u3), acc0); acc1 = fmaf(w3, bfhi(u3), acc1);
        }
        for (; k < cnt; ++k) {
            float wk = __shfl(w, k);
            int ck = __shfl(c, k);
            uint32_t u = hb[(size_t)ck * 64 + lane];
            acc0 = fmaf(wk, bflo(u), acc0);
            acc1 = fmaf(wk, bfhi(u), acc1);
        }
    }
    float2 rv = *(const float2*)&raw[(size_t)i * 128 + lane * 2];
    float o0 = EPSF * rv.x + dinv_i * acc0;
    float o1 = EPSF * rv.y + dinv_i * acc1;
    *(float2*)&h_out[(size_t)i * 128 + lane * 2] = make_float2(o0, o1);
    if (hb_out) hb_out[(size_t)i * 64 + lane] = pack2(o0, o1);
}

// ---------------- log_softmax over 64 outputs ----------------
__global__ void k_logsm(float* __restrict__ out, int N) {
    int wid = threadIdx.x >> 6, lane = threadIdx.x & 63;
    int i = blockIdx.x * 4 + wid;
    if (i >= N) return;
    float v = out[(size_t)i * 64 + lane];
    float m = v;
    for (int o = 1; o < 64; o <<= 1) m = fmaxf(m, __shfl_xor(m, o));
    float e = expf(v - m);
    float s = e;
    for (int o = 1; o < 64; o <<= 1) s += __shfl_xor(s, o);
    out[(size_t)i * 64 + lane] = v - m - logf(s);
}

extern "C" void kernel_launch(void* const* d_in, const int* in_sizes, int n_in,
                              void* d_out, int out_size, void* d_ws, size_t ws_size,
                              hipStream_t stream) {
    const float* x = (const float*)d_in[0];
    const int* ei = (const int*)d_in[1];
    const float* t1w = (const float*)d_in[2];
    const float* t1b = (const float*)d_in[3];
    const float* gw = (const float*)d_in[4];
    const float* gb = (const float*)d_in[5];
    const float* t2w = (const float*)d_in[6];
    const float* t2b = (const float*)d_in[7];
    float* out = (float*)d_out;

    const int INC = 256, HID = 128, OUTC = 64;
    const int N = in_sizes[0] / INC;
    const int E = in_sizes[1] / 2;
    const int nb = (N + 1023) / 1024;

    char* ws = (char*)d_ws;
    auto alloc = [&](size_t bytes) {
        char* p = ws;
        ws += (bytes + 255) & ~(size_t)255;
        return p;
    };
    int* flag = (int*)alloc(4);
    int* deg = (int*)alloc((size_t)N * 4);
    float* dinv = (float*)alloc((size_t)N * 4);
    int* rp = (int*)alloc((size_t)(N + 1) * 4);
    int* cur = (int*)alloc((size_t)N * 4);
    int* bsum = (int*)alloc((size_t)nb * 4);
    int* ecol = (int*)alloc((size_t)E * 4);
    float* av = (float*)alloc((size_t)N * 4);
    float2* bd = (float2*)alloc((size_t)N * 8);
    float* h0 = (float*)alloc((size_t)N * HID * 4);
    float* h1 = (float*)alloc((size_t)N * HID * 4);
    uint32_t* hb0 = (uint32_t*)alloc((size_t)N * 64 * 4);
    uint32_t* hb1 = (uint32_t*)alloc((size_t)N * 64 * 4);

    hipMemsetAsync(deg, 0, (size_t)N * 4, stream);
    k_detect<<<1, 256, 0, stream>>>(ei, flag);
    k_deg<<<(E + 255) / 256, 256, 0, stream>>>(ei, E, deg, flag);
    k_dinv<<<(N + 255) / 256, 256, 0, stream>>>(deg, dinv, N);
    k_scan1<<<nb, 1024, 0, stream>>>(deg, rp, bsum, N);
    k_scan2<<<1, 64, 0, stream>>>(bsum, nb, rp, N);
    k_scan3<<<(N + 255) / 256, 256, 0, stream>>>(rp, bsum, cur, N);
    k_scatter<<<(E + 255) / 256, 256, 0, stream>>>(ei, E, cur, ecol, flag);

    // h0 = relu(x @ t1_w^T + t1_b)  (+ bf16 shadow hb0)
    k_gemm<128, 128, 16, true, true>
        <<<dim3((N + 127) / 128, 1), 256, 0, stream>>>(x, t1w, t1b, h0, hb0, N, HID, INC);

    // layer 0: h0 -> h1 (+ bf16 shadow hb1)
    k_ab<<<(N + 3) / 4, 256, 0, stream>>>(h0, gw + 0 * 256, gb, 0, dinv, av, bd, N);
    k_agg<<<(N + 3) / 4, 256, 0, stream>>>(hb0, h0, rp, ecol, av, bd, h1, hb1, N);
    // layer 1: h1 -> h0 (raw = h0; gather source hb1, separate buffer => safe)
    k_ab<<<(N + 3) / 4, 256, 0, stream>>>(h1, gw + 1 * 256, gb, 1, dinv, av, bd, N);
    k_agg<<<(N + 3) / 4, 256, 0, stream>>>(hb1, h0, rp, ecol, av, bd, h0, nullptr, N);

    // out = h0 @ t2_w^T + t2_b, then log_softmax in place
    k_gemm<128, 64, 16, false, false>
        <<<dim3((N + 127) / 128, 1), 256, 0, stream>>>(h0, t2w, t2b, out, nullptr, N, OUTC, HID);
    k_logsm<<<(N + 3) / 4, 256, 0, stream>>>(out, N);
}

// Round 3
// 297.861 us; speedup vs baseline: 1.8667x; 1.4858x over previous
//
#include <hip/hip_runtime.h>
#include <math.h>

#define EPSF 0.3f
#define NPB 128      // nodes per bucket
#define SHB 7        // log2(NPB)
#define MAXNB 512    // max buckets (N <= 65536)
#define CHUNK 16384  // edges per block in hist/binwrite

// ---------------- bf16 helpers ----------------
__device__ __forceinline__ uint32_t f2bf(float f) {
    uint32_t u = __float_as_uint(f);
    return (u + 0x7fffu + ((u >> 16) & 1u)) >> 16;  // RNE
}
__device__ __forceinline__ uint32_t pack2(float lo, float hi) {
    return f2bf(lo) | (f2bf(hi) << 16);
}
__device__ __forceinline__ float bflo(uint32_t u) { return __uint_as_float(u << 16); }
__device__ __forceinline__ float bfhi(uint32_t u) { return __uint_as_float(u & 0xffff0000u); }

// ---------------- edge dtype probe (int32 vs int64) ----------------
__global__ void k_detect(const int* __restrict__ ei, int* __restrict__ flag) {
    __shared__ int nz;
    if (threadIdx.x == 0) nz = 0;
    __syncthreads();
    for (int t = threadIdx.x; t < 2048; t += 256)
        if (ei[2 * t + 1] != 0) atomicOr(&nz, 1);
    __syncthreads();
    if (threadIdx.x == 0) flag[0] = (nz == 0) ? 1 : 0;  // 1 => int64
}

__device__ __forceinline__ int edge_at(const int* ei, int is64, size_t idx) {
    if (is64) return (int)((const long long*)ei)[idx];
    return ei[idx];
}

// ---------------- bucket histogram: hist[bucket*nblk + blk] ----------------
__global__ __launch_bounds__(256) void k_hist(const int* __restrict__ ei, int E,
                                              const int* __restrict__ flag,
                                              int* __restrict__ hist, int nblk, int NB) {
    __shared__ int lh[MAXNB];
    for (int b = threadIdx.x; b < NB; b += 256) lh[b] = 0;
    __syncthreads();
    int is64 = flag[0];
    int base = blockIdx.x * CHUNK;
    for (int j = threadIdx.x; j < CHUNK; j += 256) {
        int e = base + j;
        if (e < E) {
            int r = edge_at(ei, is64, e);
            atomicAdd(&lh[r >> SHB], 1);
        }
    }
    __syncthreads();
    for (int b = threadIdx.x; b < NB; b += 256)
        hist[(size_t)b * nblk + blockIdx.x] = lh[b];
}

// per-bucket exclusive scan across blocks; total -> btot[bucket]
__global__ void k_scanA(int* __restrict__ hist, int nblk, int* __restrict__ btot) {
    int b = blockIdx.x;
    int lane = threadIdx.x;
    int run = 0;
    for (int seg = 0; seg < nblk; seg += 64) {
        int idx = seg + lane;
        int v = (idx < nblk) ? hist[(size_t)b * nblk + idx] : 0;
        int s = v;
        for (int o = 1; o < 64; o <<= 1) {
            int t = __shfl_up(s, o);
            if (lane >= o) s += t;
        }
        if (idx < nblk) hist[(size_t)b * nblk + idx] = run + s - v;  // exclusive
        run += __shfl(s, 63);
    }
    if (lane == 0) btot[b] = run;
}

// exclusive scan over bucket totals -> bbase[0..NB]
__global__ void k_scanB(const int* __restrict__ btot, int NB, int* __restrict__ bbase) {
    __shared__ int s[MAXNB];
    int t = threadIdx.x;
    int v = (t < NB) ? btot[t] : 0;
    s[t] = v;
    __syncthreads();
    for (int o = 1; o < MAXNB; o <<= 1) {
        int x = (t >= o) ? s[t - o] : 0;
        __syncthreads();
        s[t] += x;
        __syncthreads();
    }
    if (t < NB) bbase[t] = s[t] - v;
    if (t == MAXNB - 1) bbase[NB] = s[t];
}

// write edges into bucket-ordered ebuf (int2{row,col}); no global atomics
__global__ __launch_bounds__(256) void k_binwrite(const int* __restrict__ ei, int E,
                                                  const int* __restrict__ flag,
                                                  const int* __restrict__ hist,
                                                  const int* __restrict__ bbase,
                                                  int2* __restrict__ ebuf,
                                                  int nblk, int NB) {
    __shared__ int lcnt[MAXNB];
    for (int b = threadIdx.x; b < NB; b += 256)
        lcnt[b] = bbase[b] + hist[(size_t)b * nblk + blockIdx.x];
    __syncthreads();
    int is64 = flag[0];
    int base = blockIdx.x * CHUNK;
    for (int j = threadIdx.x; j < CHUNK; j += 256) {
        int e = base + j;
        if (e < E) {
            int r = edge_at(ei, is64, e);
            int c = edge_at(ei, is64, (size_t)E + e);
            int pos = atomicAdd(&lcnt[r >> SHB], 1);
            ebuf[pos] = make_int2(r, c);
        }
    }
}

// one block per bucket: per-node counts -> rp/dinv, then in-bucket scatter -> ecol
__global__ __launch_bounds__(256) void k_csr(const int2* __restrict__ ebuf,
                                             const int* __restrict__ bbase,
                                             int* __restrict__ rp, float* __restrict__ dinv,
                                             int* __restrict__ ecol, int N, int E, int NB) {
    __shared__ int cnt[NPB];
    __shared__ int sc[NPB];
    __shared__ int cur[NPB];
    int b = blockIdx.x;
    int tid = threadIdx.x;
    int p0 = bbase[b], p1 = bbase[b + 1];
    int n0 = b << SHB;
    if (tid < NPB) cnt[tid] = 0;
    __syncthreads();
    for (int p = p0 + tid; p < p1; p += 256)
        atomicAdd(&cnt[ebuf[p].x & (NPB - 1)], 1);
    __syncthreads();
    if (tid < NPB) sc[tid] = cnt[tid];
    __syncthreads();
    for (int o = 1; o < NPB; o <<= 1) {
        int v = (tid < NPB && tid >= o) ? sc[tid - o] : 0;
        __syncthreads();
        if (tid < NPB) sc[tid] += v;
        __syncthreads();
    }
    if (tid < NPB) {
        int off = sc[tid] - cnt[tid];  // exclusive
        cur[tid] = off;
        int node = n0 + tid;
        if (node < N) {
            rp[node] = p0 + off;
            int d = cnt[tid];
            dinv[node] = d > 0 ? rsqrtf((float)d) : 0.f;
        }
    }
    if (b == NB - 1 && tid == 0) rp[N] = E;
    __syncthreads();
    for (int p = p0 + tid; p < p1; p += 256) {
        int2 rc = ebuf[p];
        int pos = p0 + atomicAdd(&cur[rc.x & (NPB - 1)], 1);
        ecol[pos] = rc.y;
    }
}

// ---------------- tiled fp32 GEMM: C = A(MxK) * W(NxK)^T + bias ----------------
template <int BM, int BN, int BK, bool RELU, bool WBF16>
__global__ __launch_bounds__(256) void k_gemm(const float* __restrict__ A,
                                              const float* __restrict__ W,
                                              const float* __restrict__ bias,
                                              float* __restrict__ C,
                                              uint32_t* __restrict__ hb,
                                              int M, int N, int K) {
    constexpr int TM = BM / 16, TN = BN / 16;
    __shared__ float As[BK][BM + 4];
    __shared__ float Bs[BK][BN + 4];
    const int tid = threadIdx.x;
    const int tm = (tid / 16) * TM, tn = (tid % 16) * TN;
    const int m0 = blockIdx.x * BM, n0 = blockIdx.y * BN;
    float acc[TM][TN] = {};
    for (int k0 = 0; k0 < K; k0 += BK) {
#pragma unroll
        for (int r0 = 0; r0 < BM; r0 += 64) {
            int m = r0 + (tid >> 2);
            int kq = (tid & 3) * 4;
            float4 v = make_float4(0.f, 0.f, 0.f, 0.f);
            if (m0 + m < M) v = *(const float4*)&A[(size_t)(m0 + m) * K + k0 + kq];
            As[kq + 0][m] = v.x; As[kq + 1][m] = v.y;
            As[kq + 2][m] = v.z; As[kq + 3][m] = v.w;
        }
#pragma unroll
        for (int r0 = 0; r0 < BN; r0 += 64) {
            int n = r0 + (tid >> 2);
            int kq = (tid & 3) * 4;
            float4 v = *(const float4*)&W[(size_t)(n0 + n) * K + k0 + kq];
            Bs[kq + 0][n] = v.x; Bs[kq + 1][n] = v.y;
            Bs[kq + 2][n] = v.z; Bs[kq + 3][n] = v.w;
        }
        __syncthreads();
#pragma unroll
        for (int kk = 0; kk < BK; ++kk) {
            float a[TM], b[TN];
#pragma unroll
            for (int x = 0; x < TM; x += 4)
                *(float4*)&a[x] = *(const float4*)&As[kk][tm + x];
#pragma unroll
            for (int x = 0; x < TN; x += 4)
                *(float4*)&b[x] = *(const float4*)&Bs[kk][tn + x];
#pragma unroll
            for (int mi = 0; mi < TM; ++mi)
#pragma unroll
                for (int ni = 0; ni < TN; ++ni)
                    acc[mi][ni] = fmaf(a[mi], b[ni], acc[mi][ni]);
        }
        __syncthreads();
    }
#pragma unroll
    for (int mi = 0; mi < TM; ++mi) {
        int m = m0 + tm + mi;
        if (m < M) {
            float vv[TN];
#pragma unroll
            for (int ni = 0; ni < TN; ++ni) {
                float v = acc[mi][ni] + bias[n0 + tn + ni];
                if (RELU) v = fmaxf(v, 0.f);
                C[(size_t)m * N + n0 + tn + ni] = v;
                vv[ni] = v;
            }
            if (WBF16) {
                uint4 pk;
                pk.x = pack2(vv[0], vv[1]);
                pk.y = pack2(vv[2], vv[3]);
                pk.z = pack2(vv[4], vv[5]);
                pk.w = pack2(vv[6], vv[7]);
                *(uint4*)&hb[(size_t)m * 64 + (size_t)(n0 + tn) / 2] = pk;
            }
        }
    }
}

// ---------------- per-node gate scalars ----------------
// av[i] = h[i].gw_i + gate_b[layer];  bd[i] = {h[i].gw_j, dinv[i]}
template <bool BF>
__global__ void k_ab(const float* __restrict__ h, const uint32_t* __restrict__ hbv,
                     const float* __restrict__ gw, const float* __restrict__ gb, int layer,
                     const float* __restrict__ dinv,
                     float* __restrict__ av, float2* __restrict__ bd, int N) {
    int wid = threadIdx.x >> 6, lane = threadIdx.x & 63;
    int i = blockIdx.x * 4 + wid;
    if (i >= N) return;
    float hx, hy;
    if (BF) {
        uint32_t u = hbv[(size_t)i * 64 + lane];
        hx = bflo(u); hy = bfhi(u);
    } else {
        float2 hv = *(const float2*)&h[(size_t)i * 128 + lane * 2];
        hx = hv.x; hy = hv.y;
    }
    float2 wi = *(const float2*)&gw[lane * 2];
    float2 wj = *(const float2*)&gw[128 + lane * 2];
    float pa = hx * wi.x + hy * wi.y;
    float pb = hx * wj.x + hy * wj.y;
    for (int o = 1; o < 64; o <<= 1) {
        pa += __shfl_xor(pa, o);
        pb += __shfl_xor(pb, o);
    }
    if (lane == 0) {
        av[i] = pa + gb[layer];
        bd[i] = make_float2(pb, dinv[i]);
    }
}

// ---------------- aggregation ----------------
__global__ void k_agg(const uint32_t* __restrict__ hb, const float* __restrict__ raw,
                      const int* __restrict__ rp, const int* __restrict__ ecol,
                      const float* __restrict__ av, const float2* __restrict__ bd,
                      float* __restrict__ h_out, uint32_t* __restrict__ hb_out, int N) {
    int wid = threadIdx.x >> 6, lane = threadIdx.x & 63;
    int i = blockIdx.x * 4 + wid;
    if (i >= N) return;
    float a_i = av[i];
    float dinv_i = bd[i].y;
    int p0 = rp[i], p1 = rp[i + 1];
    float acc0 = 0.f, acc1 = 0.f;
    for (int base = p0; base < p1; base += 64) {
        int p = base + lane;
        float w = 0.f;
        int c = 0;
        if (p < p1) {
            c = ecol[p];
            float2 t = bd[c];
            w = tanhf(a_i + t.x) * t.y;
        }
        int cnt = min(64, p1 - base);
        int k = 0;
        for (; k + 4 <= cnt; k += 4) {
            float w0 = __shfl(w, k + 0), w1 = __shfl(w, k + 1);
            float w2 = __shfl(w, k + 2), w3 = __shfl(w, k + 3);
            int c0 = __shfl(c, k + 0), c1 = __shfl(c, k + 1);
            int c2 = __shfl(c, k + 2), c3 = __shfl(c, k + 3);
            uint32_t u0 = hb[(size_t)c0 * 64 + lane];
            uint32_t u1 = hb[(size_t)c1 * 64 + lane];
            uint32_t u2 = hb[(size_t)c2 * 64 + lane];
            uint32_t u3 = hb[(size_t)c3 * 64 + lane];
            acc0 = fmaf(w0, bflo(u0), acc0); acc1 = fmaf(w0, bfhi(u0), acc1);
            acc0 = fmaf(w1, bflo(u1), acc0); acc1 = fmaf(w1, bfhi(u1), acc1);
            acc0 = fmaf(w2, bflo(u2), acc0); acc1 = fmaf(w2, bfhi(u2), acc1);
            acc0 = fmaf(w3, bflo(u3), acc0); acc1 = fmaf(w3, bfhi(u3), acc1);
        }
        for (; k < cnt; ++k) {
            float wk = __shfl(w, k);
            int ck = __shfl(c, k);
            uint32_t u = hb[(size_t)ck * 64 + lane];
            acc0 = fmaf(wk, bflo(u), acc0);
            acc1 = fmaf(wk, bfhi(u), acc1);
        }
    }
    float2 rv = *(const float2*)&raw[(size_t)i * 128 + lane * 2];
    float o0 = EPSF * rv.x + dinv_i * acc0;
    float o1 = EPSF * rv.y + dinv_i * acc1;
    if (h_out) *(float2*)&h_out[(size_t)i * 128 + lane * 2] = make_float2(o0, o1);
    if (hb_out) hb_out[(size_t)i * 64 + lane] = pack2(o0, o1);
}

// ---------------- log_softmax over 64 outputs ----------------
__global__ void k_logsm(float* __restrict__ out, int N) {
    int wid = threadIdx.x >> 6, lane = threadIdx.x & 63;
    int i = blockIdx.x * 4 + wid;
    if (i >= N) return;
    float v = out[(size_t)i * 64 + lane];
    float m = v;
    for (int o = 1; o < 64; o <<= 1) m = fmaxf(m, __shfl_xor(m, o));
    float e = expf(v - m);
    float s = e;
    for (int o = 1; o < 64; o <<= 1) s += __shfl_xor(s, o);
    out[(size_t)i * 64 + lane] = v - m - logf(s);
}

extern "C" void kernel_launch(void* const* d_in, const int* in_sizes, int n_in,
                              void* d_out, int out_size, void* d_ws, size_t ws_size,
                              hipStream_t stream) {
    const float* x = (const float*)d_in[0];
    const int* ei = (const int*)d_in[1];
    const float* t1w = (const float*)d_in[2];
    const float* t1b = (const float*)d_in[3];
    const float* gw = (const float*)d_in[4];
    const float* gb = (const float*)d_in[5];
    const float* t2w = (const float*)d_in[6];
    const float* t2b = (const float*)d_in[7];
    float* out = (float*)d_out;

    const int INC = 256, HID = 128, OUTC = 64;
    const int N = in_sizes[0] / INC;
    const int E = in_sizes[1] / 2;
    const int NB = (N + NPB - 1) >> SHB;
    const int nblk = (E + CHUNK - 1) / CHUNK;

    char* ws = (char*)d_ws;
    auto alloc = [&](size_t bytes) {
        char* p = ws;
        ws += (bytes + 255) & ~(size_t)255;
        return p;
    };
    int* flag = (int*)alloc(4);
    int* hist = (int*)alloc((size_t)NB * nblk * 4);
    int* btot = (int*)alloc((size_t)NB * 4);
    int* bbase = (int*)alloc((size_t)(NB + 1) * 4);
    int2* ebuf = (int2*)alloc((size_t)E * 8);
    int* rp = (int*)alloc((size_t)(N + 1) * 4);
    float* dinv = (float*)alloc((size_t)N * 4);
    int* ecol = (int*)alloc((size_t)E * 4);
    float* av = (float*)alloc((size_t)N * 4);
    float2* bd = (float2*)alloc((size_t)N * 8);
    float* h0 = (float*)alloc((size_t)N * HID * 4);
    uint32_t* hb0 = (uint32_t*)alloc((size_t)N * 64 * 4);
    uint32_t* hb1 = (uint32_t*)alloc((size_t)N * 64 * 4);

    // ---- CSR build (no global atomics) ----
    k_detect<<<1, 256, 0, stream>>>(ei, flag);
    k_hist<<<nblk, 256, 0, stream>>>(ei, E, flag, hist, nblk, NB);
    k_scanA<<<NB, 64, 0, stream>>>(hist, nblk, btot);
    k_scanB<<<1, MAXNB, 0, stream>>>(btot, NB, bbase);
    k_binwrite<<<nblk, 256, 0, stream>>>(ei, E, flag, hist, bbase, ebuf, nblk, NB);
    k_csr<<<NB, 256, 0, stream>>>(ebuf, bbase, rp, dinv, ecol, N, E, NB);

    // ---- h0 = relu(x @ t1_w^T + t1_b)  (+ bf16 shadow hb0) ----
    k_gemm<128, 128, 16, true, true>
        <<<dim3((N + 127) / 128, 1), 256, 0, stream>>>(x, t1w, t1b, h0, hb0, N, HID, INC);

    // ---- layer 0: h0 -> hb1 (bf16 only) ----
    k_ab<false><<<(N + 3) / 4, 256, 0, stream>>>(h0, nullptr, gw + 0 * 256, gb, 0, dinv, av, bd, N);
    k_agg<<<(N + 3) / 4, 256, 0, stream>>>(hb0, h0, rp, ecol, av, bd, nullptr, hb1, N);
    // ---- layer 1: hb1 -> h0 (fp32, in-place-safe) ----
    k_ab<true><<<(N + 3) / 4, 256, 0, stream>>>(nullptr, hb1, gw + 1 * 256, gb, 1, dinv, av, bd, N);
    k_agg<<<(N + 3) / 4, 256, 0, stream>>>(hb1, h0, rp, ecol, av, bd, h0, nullptr, N);

    // ---- out = h0 @ t2_w^T + t2_b, then log_softmax ----
    k_gemm<128, 64, 16, false, false>
        <<<dim3((N + 127) / 128, 1), 256, 0, stream>>>(h0, t2w, t2b, out, nullptr, N, OUTC, HID);
    k_logsm<<<(N + 3) / 4, 256, 0, stream>>>(out, N);
}

// Round 4
// 247.350 us; speedup vs baseline: 2.2479x; 1.2042x over previous
//
#include <hip/hip_runtime.h>
#include <math.h>

#define EPSF 0.3f
#define NPB 128      // nodes per bucket
#define SHB 7        // log2(NPB)
#define MAXNB 512    // max buckets
#define CHUNK 16384  // edges per block in hist/binwrite

typedef __attribute__((ext_vector_type(8))) short bf16x8;
typedef __attribute__((ext_vector_type(4))) float f32x4;

// ---------------- bf16 helpers ----------------
__device__ __forceinline__ uint32_t f2bf(float f) {
    uint32_t u = __float_as_uint(f);
    return (u + 0x7fffu + ((u >> 16) & 1u)) >> 16;  // RNE
}
__device__ __forceinline__ uint32_t pack2(float lo, float hi) {
    return f2bf(lo) | (f2bf(hi) << 16);
}
__device__ __forceinline__ float bflo(uint32_t u) { return __uint_as_float(u << 16); }
__device__ __forceinline__ float bfhi(uint32_t u) { return __uint_as_float(u & 0xffff0000u); }

// ---------------- edge dtype probe (int32 vs int64) ----------------
__global__ void k_detect(const int* __restrict__ ei, int* __restrict__ flag) {
    __shared__ int nz;
    if (threadIdx.x == 0) nz = 0;
    __syncthreads();
    for (int t = threadIdx.x; t < 2048; t += 256)
        if (ei[2 * t + 1] != 0) atomicOr(&nz, 1);
    __syncthreads();
    if (threadIdx.x == 0) flag[0] = (nz == 0) ? 1 : 0;  // 1 => int64
}

__device__ __forceinline__ int edge_at(const int* ei, int is64, size_t idx) {
    if (is64) return (int)((const long long*)ei)[idx];
    return ei[idx];
}

// ---------------- bucket histogram ----------------
__global__ __launch_bounds__(256) void k_hist(const int* __restrict__ ei, int E,
                                              const int* __restrict__ flag,
                                              int* __restrict__ hist, int nblk, int NB) {
    __shared__ int lh[MAXNB];
    for (int b = threadIdx.x; b < NB; b += 256) lh[b] = 0;
    __syncthreads();
    int is64 = flag[0];
    int base = blockIdx.x * CHUNK;
    for (int j = threadIdx.x; j < CHUNK; j += 256) {
        int e = base + j;
        if (e < E) {
            int r = edge_at(ei, is64, e);
            atomicAdd(&lh[r >> SHB], 1);
        }
    }
    __syncthreads();
    for (int b = threadIdx.x; b < NB; b += 256)
        hist[(size_t)b * nblk + blockIdx.x] = lh[b];
}

__global__ void k_scanA(int* __restrict__ hist, int nblk, int* __restrict__ btot) {
    int b = blockIdx.x;
    int lane = threadIdx.x;
    int run = 0;
    for (int seg = 0; seg < nblk; seg += 64) {
        int idx = seg + lane;
        int v = (idx < nblk) ? hist[(size_t)b * nblk + idx] : 0;
        int s = v;
        for (int o = 1; o < 64; o <<= 1) {
            int t = __shfl_up(s, o);
            if (lane >= o) s += t;
        }
        if (idx < nblk) hist[(size_t)b * nblk + idx] = run + s - v;
        run += __shfl(s, 63);
    }
    if (lane == 0) btot[b] = run;
}

__global__ void k_scanB(const int* __restrict__ btot, int NB, int* __restrict__ bbase) {
    __shared__ int s[MAXNB];
    int t = threadIdx.x;
    int v = (t < NB) ? btot[t] : 0;
    s[t] = v;
    __syncthreads();
    for (int o = 1; o < MAXNB; o <<= 1) {
        int x = (t >= o) ? s[t - o] : 0;
        __syncthreads();
        s[t] += x;
        __syncthreads();
    }
    if (t < NB) bbase[t] = s[t] - v;
    if (t == MAXNB - 1) bbase[NB] = s[t];
}

__global__ __launch_bounds__(256) void k_binwrite(const int* __restrict__ ei, int E,
                                                  const int* __restrict__ flag,
                                                  const int* __restrict__ hist,
                                                  const int* __restrict__ bbase,
                                                  int2* __restrict__ ebuf,
                                                  int nblk, int NB) {
    __shared__ int lcnt[MAXNB];
    for (int b = threadIdx.x; b < NB; b += 256)
        lcnt[b] = bbase[b] + hist[(size_t)b * nblk + blockIdx.x];
    __syncthreads();
    int is64 = flag[0];
    int base = blockIdx.x * CHUNK;
    for (int j = threadIdx.x; j < CHUNK; j += 256) {
        int e = base + j;
        if (e < E) {
            int r = edge_at(ei, is64, e);
            int c = edge_at(ei, is64, (size_t)E + e);
            int pos = atomicAdd(&lcnt[r >> SHB], 1);
            ebuf[pos] = make_int2(r, c);
        }
    }
}

__global__ __launch_bounds__(256) void k_csr(const int2* __restrict__ ebuf,
                                             const int* __restrict__ bbase,
                                             int* __restrict__ rp, float* __restrict__ dinv,
                                             int* __restrict__ ecol, int N, int E, int NB) {
    __shared__ int cnt[NPB];
    __shared__ int sc[NPB];
    __shared__ int cur[NPB];
    int b = blockIdx.x;
    int tid = threadIdx.x;
    int p0 = bbase[b], p1 = bbase[b + 1];
    int n0 = b << SHB;
    if (tid < NPB) cnt[tid] = 0;
    __syncthreads();
    for (int p = p0 + tid; p < p1; p += 256)
        atomicAdd(&cnt[ebuf[p].x & (NPB - 1)], 1);
    __syncthreads();
    if (tid < NPB) sc[tid] = cnt[tid];
    __syncthreads();
    for (int o = 1; o < NPB; o <<= 1) {
        int v = (tid < NPB && tid >= o) ? sc[tid - o] : 0;
        __syncthreads();
        if (tid < NPB) sc[tid] += v;
        __syncthreads();
    }
    if (tid < NPB) {
        int off = sc[tid] - cnt[tid];
        cur[tid] = off;
        int node = n0 + tid;
        if (node < N) {
            rp[node] = p0 + off;
            int d = cnt[tid];
            dinv[node] = d > 0 ? rsqrtf((float)d) : 0.f;
        }
    }
    if (b == NB - 1 && tid == 0) rp[N] = E;
    __syncthreads();
    for (int p = p0 + tid; p < p1; p += 256) {
        int2 rc = ebuf[p];
        int pos = p0 + atomicAdd(&cur[rc.x & (NPB - 1)], 1);
        ecol[pos] = rc.y;
    }
}

// ---------------- GEMM1 (MFMA bf16): hb = relu(x @ t1_w^T + b) as bf16 ----------------
// M x 256 fp32 in, M x 128 bf16 (packed u32 pairs) out. 128x128 tile, BK=64, 4 waves 2x2.
__global__ __launch_bounds__(256) void k_gemm1(const float* __restrict__ A,
                                               const float* __restrict__ W,
                                               const float* __restrict__ bias,
                                               uint32_t* __restrict__ hb, int M) {
    __shared__ char As[128 * 128];  // 128 rows x 64 bf16, XOR-swizzled
    __shared__ char Bs[128 * 128];
    const int tid = threadIdx.x;
    const int lane = tid & 63;
    const int wave = tid >> 6;
    const int wr = wave >> 1, wc = wave & 1;
    const int m0 = blockIdx.x * 128;
    const int lrow = lane & 15, lkg = lane >> 4;
    const int sr = tid >> 3;        // staging row 0..31
    const int sc = (tid & 7) * 8;   // staging float col

    f32x4 acc[4][4];
#pragma unroll
    for (int mi = 0; mi < 4; ++mi)
#pragma unroll
        for (int ni = 0; ni < 4; ++ni) acc[mi][ni] = (f32x4){0.f, 0.f, 0.f, 0.f};

    for (int t = 0; t < 4; ++t) {
        const int k0 = t * 64;
#pragma unroll
        for (int i = 0; i < 4; ++i) {
            int r = i * 32 + sr;
            float4 v0 = make_float4(0.f, 0.f, 0.f, 0.f), v1 = v0;
            if (m0 + r < M) {
                const float* p = &A[(size_t)(m0 + r) * 256 + k0 + sc];
                v0 = *(const float4*)p;
                v1 = *(const float4*)(p + 4);
            }
            uint4 pk = make_uint4(pack2(v0.x, v0.y), pack2(v0.z, v0.w),
                                  pack2(v1.x, v1.y), pack2(v1.z, v1.w));
            uint32_t off = (uint32_t)(r * 128 + sc * 2);
            *(uint4*)(As + (off ^ ((r & 7) << 4))) = pk;
        }
#pragma unroll
        for (int i = 0; i < 4; ++i) {
            int r = i * 32 + sr;
            const float* p = &W[(size_t)r * 256 + k0 + sc];
            float4 v0 = *(const float4*)p;
            float4 v1 = *(const float4*)(p + 4);
            uint4 pk = make_uint4(pack2(v0.x, v0.y), pack2(v0.z, v0.w),
                                  pack2(v1.x, v1.y), pack2(v1.z, v1.w));
            uint32_t off = (uint32_t)(r * 128 + sc * 2);
            *(uint4*)(Bs + (off ^ ((r & 7) << 4))) = pk;
        }
        __syncthreads();
#pragma unroll
        for (int ks = 0; ks < 2; ++ks) {
            bf16x8 af[4], bfr[4];
#pragma unroll
            for (int mi = 0; mi < 4; ++mi) {
                int r = wr * 64 + mi * 16 + lrow;
                uint32_t off = (uint32_t)(r * 128 + ks * 64 + lkg * 16);
                af[mi] = *(const bf16x8*)(As + (off ^ ((r & 7) << 4)));
            }
#pragma unroll
            for (int ni = 0; ni < 4; ++ni) {
                int r = wc * 64 + ni * 16 + lrow;
                uint32_t off = (uint32_t)(r * 128 + ks * 64 + lkg * 16);
                bfr[ni] = *(const bf16x8*)(Bs + (off ^ ((r & 7) << 4)));
            }
#pragma unroll
            for (int mi = 0; mi < 4; ++mi)
#pragma unroll
                for (int ni = 0; ni < 4; ++ni)
                    acc[mi][ni] = __builtin_amdgcn_mfma_f32_16x16x32_bf16(
                        af[mi], bfr[ni], acc[mi][ni], 0, 0, 0);
        }
        __syncthreads();
    }
    // epilogue: relu + bias, pack bf16 pairs via shfl_xor(1)
#pragma unroll
    for (int mi = 0; mi < 4; ++mi) {
#pragma unroll
        for (int ni = 0; ni < 4; ++ni) {
            int n = wc * 64 + ni * 16 + lrow;
            float bv = bias[n];
#pragma unroll
            for (int q = 0; q < 4; ++q) {
                float v = fmaxf(acc[mi][ni][q] + bv, 0.f);
                float vp = __shfl_xor(v, 1);
                int m = m0 + wr * 64 + mi * 16 + lkg * 4 + q;
                if (!(lane & 1) && m < M)
                    hb[(size_t)m * 64 + (n >> 1)] = pack2(v, vp);
            }
        }
    }
}

// ---------------- GEMM2 (MFMA bf16): out = hb2 @ t2_w^T + b (fp32 out) ----------------
// A: M x 128 bf16 (u32-packed). W: 64 x 128 fp32. 128x64 tile, BK=64, 4 waves 2x2 (64x32 each).
__global__ __launch_bounds__(256) void k_gemm2(const uint32_t* __restrict__ Abf,
                                               const float* __restrict__ W,
                                               const float* __restrict__ bias,
                                               float* __restrict__ out, int M) {
    __shared__ char As[128 * 128];
    __shared__ char Bs[64 * 128];
    const int tid = threadIdx.x;
    const int lane = tid & 63;
    const int wave = tid >> 6;
    const int wr = wave >> 1, wc = wave & 1;
    const int m0 = blockIdx.x * 128;
    const int lrow = lane & 15, lkg = lane >> 4;

    f32x4 acc[4][2];
#pragma unroll
    for (int mi = 0; mi < 4; ++mi)
#pragma unroll
        for (int ni = 0; ni < 2; ++ni) acc[mi][ni] = (f32x4){0.f, 0.f, 0.f, 0.f};

    for (int t = 0; t < 2; ++t) {
#pragma unroll
        for (int i = 0; i < 4; ++i) {
            int r = i * 32 + (tid >> 3);
            uint4 v = make_uint4(0u, 0u, 0u, 0u);
            if (m0 + r < M)
                v = *(const uint4*)&Abf[(size_t)(m0 + r) * 64 + t * 32 + (tid & 7) * 4];
            uint32_t off = (uint32_t)(r * 128 + (tid & 7) * 16);
            *(uint4*)(As + (off ^ ((r & 7) << 4))) = v;
        }
#pragma unroll
        for (int i = 0; i < 2; ++i) {
            int r = i * 32 + (tid >> 3);
            const float* p = &W[(size_t)r * 128 + t * 64 + (tid & 7) * 8];
            float4 v0 = *(const float4*)p, v1 = *(const float4*)(p + 4);
            uint4 pk = make_uint4(pack2(v0.x, v0.y), pack2(v0.z, v0.w),
                                  pack2(v1.x, v1.y), pack2(v1.z, v1.w));
            uint32_t off = (uint32_t)(r * 128 + (tid & 7) * 16);
            *(uint4*)(Bs + (off ^ ((r & 7) << 4))) = pk;
        }
        __syncthreads();
#pragma unroll
        for (int ks = 0; ks < 2; ++ks) {
            bf16x8 af[4], bfr[2];
#pragma unroll
            for (int mi = 0; mi < 4; ++mi) {
                int r = wr * 64 + mi * 16 + lrow;
                uint32_t off = (uint32_t)(r * 128 + ks * 64 + lkg * 16);
                af[mi] = *(const bf16x8*)(As + (off ^ ((r & 7) << 4)));
            }
#pragma unroll
            for (int ni = 0; ni < 2; ++ni) {
                int r = wc * 32 + ni * 16 + lrow;
                uint32_t off = (uint32_t)(r * 128 + ks * 64 + lkg * 16);
                bfr[ni] = *(const bf16x8*)(Bs + (off ^ ((r & 7) << 4)));
            }
#pragma unroll
            for (int mi = 0; mi < 4; ++mi)
#pragma unroll
                for (int ni = 0; ni < 2; ++ni)
                    acc[mi][ni] = __builtin_amdgcn_mfma_f32_16x16x32_bf16(
                        af[mi], bfr[ni], acc[mi][ni], 0, 0, 0);
        }
        __syncthreads();
    }
#pragma unroll
    for (int mi = 0; mi < 4; ++mi) {
#pragma unroll
        for (int ni = 0; ni < 2; ++ni) {
            int n = wc * 32 + ni * 16 + lrow;
            float bv = bias[n];
#pragma unroll
            for (int q = 0; q < 4; ++q) {
                int m = m0 + wr * 64 + mi * 16 + lkg * 4 + q;
                if (m < M) out[(size_t)m * 64 + n] = acc[mi][ni][q] + bv;
            }
        }
    }
}

// ---------------- per-node gate scalars (bf16 h) ----------------
__global__ void k_ab(const uint32_t* __restrict__ hbv, const float* __restrict__ gw,
                     const float* __restrict__ gb, int layer,
                     const float* __restrict__ dinv,
                     float* __restrict__ av, float2* __restrict__ bd, int N) {
    int wid = threadIdx.x >> 6, lane = threadIdx.x & 63;
    int i = blockIdx.x * 4 + wid;
    if (i >= N) return;
    uint32_t u = hbv[(size_t)i * 64 + lane];
    float hx = bflo(u), hy = bfhi(u);
    float2 wi = *(const float2*)&gw[lane * 2];
    float2 wj = *(const float2*)&gw[128 + lane * 2];
    float pa = hx * wi.x + hy * wi.y;
    float pb = hx * wj.x + hy * wj.y;
    for (int o = 1; o < 64; o <<= 1) {
        pa += __shfl_xor(pa, o);
        pb += __shfl_xor(pb, o);
    }
    if (lane == 0) {
        av[i] = pa + gb[layer];
        bd[i] = make_float2(pb, dinv[i]);
    }
}

// ---------------- aggregation (all-bf16 state) ----------------
__global__ void k_agg(const uint32_t* __restrict__ hb, const uint32_t* __restrict__ raw,
                      const int* __restrict__ rp, const int* __restrict__ ecol,
                      const float* __restrict__ av, const float2* __restrict__ bd,
                      uint32_t* __restrict__ hb_out, int N) {
    int wid = threadIdx.x >> 6, lane = threadIdx.x & 63;
    int i = blockIdx.x * 4 + wid;
    if (i >= N) return;
    float a_i = av[i];
    float dinv_i = bd[i].y;
    int p0 = rp[i], p1 = rp[i + 1];
    float acc0 = 0.f, acc1 = 0.f;
    for (int base = p0; base < p1; base += 64) {
        int p = base + lane;
        float w = 0.f;
        int c = 0;
        if (p < p1) {
            c = ecol[p];
            float2 t = bd[c];
            w = tanhf(a_i + t.x) * t.y;
        }
        int cnt = min(64, p1 - base);
        int k = 0;
        for (; k + 4 <= cnt; k += 4) {
            float w0 = __shfl(w, k + 0), w1 = __shfl(w, k + 1);
            float w2 = __shfl(w, k + 2), w3 = __shfl(w, k + 3);
            int c0 = __shfl(c, k + 0), c1 = __shfl(c, k + 1);
            int c2 = __shfl(c, k + 2), c3 = __shfl(c, k + 3);
            uint32_t u0 = hb[(size_t)c0 * 64 + lane];
            uint32_t u1 = hb[(size_t)c1 * 64 + lane];
            uint32_t u2 = hb[(size_t)c2 * 64 + lane];
            uint32_t u3 = hb[(size_t)c3 * 64 + lane];
            acc0 = fmaf(w0, bflo(u0), acc0); acc1 = fmaf(w0, bfhi(u0), acc1);
            acc0 = fmaf(w1, bflo(u1), acc0); acc1 = fmaf(w1, bfhi(u1), acc1);
            acc0 = fmaf(w2, bflo(u2), acc0); acc1 = fmaf(w2, bfhi(u2), acc1);
            acc0 = fmaf(w3, bflo(u3), acc0); acc1 = fmaf(w3, bfhi(u3), acc1);
        }
        for (; k < cnt; ++k) {
            float wk = __shfl(w, k);
            int ck = __shfl(c, k);
            uint32_t u = hb[(size_t)ck * 64 + lane];
            acc0 = fmaf(wk, bflo(u), acc0);
            acc1 = fmaf(wk, bfhi(u), acc1);
        }
    }
    uint32_t ru = raw[(size_t)i * 64 + lane];
    float o0 = EPSF * bflo(ru) + dinv_i * acc0;
    float o1 = EPSF * bfhi(ru) + dinv_i * acc1;
    hb_out[(size_t)i * 64 + lane] = pack2(o0, o1);
}

// ---------------- log_softmax over 64 outputs ----------------
__global__ void k_logsm(float* __restrict__ out, int N) {
    int wid = threadIdx.x >> 6, lane = threadIdx.x & 63;
    int i = blockIdx.x * 4 + wid;
    if (i >= N) return;
    float v = out[(size_t)i * 64 + lane];
    float m = v;
    for (int o = 1; o < 64; o <<= 1) m = fmaxf(m, __shfl_xor(m, o));
    float e = expf(v - m);
    float s = e;
    for (int o = 1; o < 64; o <<= 1) s += __shfl_xor(s, o);
    out[(size_t)i * 64 + lane] = v - m - logf(s);
}

extern "C" void kernel_launch(void* const* d_in, const int* in_sizes, int n_in,
                              void* d_out, int out_size, void* d_ws, size_t ws_size,
                              hipStream_t stream) {
    const float* x = (const float*)d_in[0];
    const int* ei = (const int*)d_in[1];
    const float* t1w = (const float*)d_in[2];
    const float* t1b = (const float*)d_in[3];
    const float* gw = (const float*)d_in[4];
    const float* gb = (const float*)d_in[5];
    const float* t2w = (const float*)d_in[6];
    const float* t2b = (const float*)d_in[7];
    float* out = (float*)d_out;

    const int INC = 256;
    const int N = in_sizes[0] / INC;
    const int E = in_sizes[1] / 2;
    const int NB = (N + NPB - 1) >> SHB;
    const int nblk = (E + CHUNK - 1) / CHUNK;

    char* ws = (char*)d_ws;
    auto alloc = [&](size_t bytes) {
        char* p = ws;
        ws += (bytes + 255) & ~(size_t)255;
        return p;
    };
    int* flag = (int*)alloc(4);
    int* hist = (int*)alloc((size_t)NB * nblk * 4);
    int* btot = (int*)alloc((size_t)NB * 4);
    int* bbase = (int*)alloc((size_t)(NB + 1) * 4);
    int2* ebuf = (int2*)alloc((size_t)E * 8);
    int* rp = (int*)alloc((size_t)(N + 1) * 4);
    float* dinv = (float*)alloc((size_t)N * 4);
    int* ecol = (int*)alloc((size_t)E * 4);
    float* av = (float*)alloc((size_t)N * 4);
    float2* bd = (float2*)alloc((size_t)N * 8);
    uint32_t* hb0 = (uint32_t*)alloc((size_t)N * 64 * 4);
    uint32_t* hb1 = (uint32_t*)alloc((size_t)N * 64 * 4);
    uint32_t* hb2 = (uint32_t*)alloc((size_t)N * 64 * 4);

    // ---- CSR build (no global atomics) ----
    k_detect<<<1, 256, 0, stream>>>(ei, flag);
    k_hist<<<nblk, 256, 0, stream>>>(ei, E, flag, hist, nblk, NB);
    k_scanA<<<NB, 64, 0, stream>>>(hist, nblk, btot);
    k_scanB<<<1, MAXNB, 0, stream>>>(btot, NB, bbase);
    k_binwrite<<<nblk, 256, 0, stream>>>(ei, E, flag, hist, bbase, ebuf, nblk, NB);
    k_csr<<<NB, 256, 0, stream>>>(ebuf, bbase, rp, dinv, ecol, N, E, NB);

    // ---- hb0 = relu(x @ t1_w^T + t1_b) (bf16, MFMA) ----
    k_gemm1<<<(N + 127) / 128, 256, 0, stream>>>(x, t1w, t1b, hb0, N);

    // ---- layer 0: hb0 -> hb1 ----
    k_ab<<<(N + 3) / 4, 256, 0, stream>>>(hb0, gw + 0 * 256, gb, 0, dinv, av, bd, N);
    k_agg<<<(N + 3) / 4, 256, 0, stream>>>(hb0, hb0, rp, ecol, av, bd, hb1, N);
    // ---- layer 1: hb1 -> hb2 (raw = hb0) ----
    k_ab<<<(N + 3) / 4, 256, 0, stream>>>(hb1, gw + 1 * 256, gb, 1, dinv, av, bd, N);
    k_agg<<<(N + 3) / 4, 256, 0, stream>>>(hb1, hb0, rp, ecol, av, bd, hb2, N);

    // ---- out = hb2 @ t2_w^T + t2_b (MFMA), then log_softmax ----
    k_gemm2<<<(N + 127) / 128, 256, 0, stream>>>(hb2, t2w, t2b, out, N);
    k_logsm<<<(N + 3) / 4, 256, 0, stream>>>(out, N);
}